// Round 12
// baseline (232.859 us; speedup 1.0000x reference)
//
#include <hip/hip_runtime.h>
#include <hip/hip_bf16.h>

// LQR-MPC: T=50, N=12, M=4, NSC=16, NB=8192.
// == R11 (validated 186-188us) + ONE change: vn publish merged into the U
// write phase (vn rides float-offset 240 of the U buffer, same barrier) ->
// 3 barrier-phases/step instead of 4, svv buffer deleted. Bit-identical
// arithmetic; only data placement changes. This isolates R8's phase-merge
// (R9 convicted Cholesky alone; this run exonerates-or-convicts the merge).
// CHOLESKY BANNED (NaN R1/R8/R9); LU validated R3-R7/R10/R11.
// U-SCHEME: lane c holds Vn[:,c] (= V row c by symmetry) in registers;
// U row c = V[c,:]*F from s_load F rows (scalar path). One 16x16 U
// transpose via LDS per step. Single-wave blocks: DS in-order ->
// wave_barrier(). Vn = Qxx + Qxu*K exactly (K^T Qux + K^T Quu K cancels).
#define TT 50
#define NBB 8192
#define QS  20    // Qt col stride (floats)
#define QTE 88    // Qt per-elem stride
#define US  20    // U row stride (floats)
#define UES 264   // U per-elem stride: 12 rows*20 + v-slot at 240..251 (264%32=8)

typedef float f32x2 __attribute__((ext_vector_type(2)));

__device__ __forceinline__ unsigned short f2bf(float f) {
  unsigned int u = __float_as_uint(f);
  u = (u + 0x7FFFu + ((u >> 16) & 1u)) >> 16;   // RNE
  return (unsigned short)u;
}
__device__ __forceinline__ float bf2f(unsigned short h) {
  return __uint_as_float(((unsigned int)h) << 16);
}
__device__ __forceinline__ float rrsum16(float v) {
  int t;
  t = __builtin_amdgcn_update_dpp(0, __float_as_int(v), 0x128, 0xF, 0xF, true); v += __int_as_float(t);
  t = __builtin_amdgcn_update_dpp(0, __float_as_int(v), 0x124, 0xF, 0xF, true); v += __int_as_float(t);
  t = __builtin_amdgcn_update_dpp(0, __float_as_int(v), 0x122, 0xF, 0xF, true); v += __int_as_float(t);
  t = __builtin_amdgcn_update_dpp(0, __float_as_int(v), 0x121, 0xF, 0xF, true); v += __int_as_float(t);
  return v;
}

// Branchless partial-pivot LU on [Quu | r1 | r2]; s1 = -Quu^-1 r1, s2 = -Quu^-1 r2
__device__ __forceinline__ void lu46(const float4 q0, const float4 q1, const float4 q2, const float4 q3,
                                     const float4 r1, const float4 r2, float4& s1, float4& s2) {
  float M[4][6];
  M[0][0]=q0.x; M[1][0]=q0.y; M[2][0]=q0.z; M[3][0]=q0.w;
  M[0][1]=q1.x; M[1][1]=q1.y; M[2][1]=q1.z; M[3][1]=q1.w;
  M[0][2]=q2.x; M[1][2]=q2.y; M[2][2]=q2.z; M[3][2]=q2.w;
  M[0][3]=q3.x; M[1][3]=q3.y; M[2][3]=q3.z; M[3][3]=q3.w;
  M[0][4]=r1.x; M[1][4]=r1.y; M[2][4]=r1.z; M[3][4]=r1.w;
  M[0][5]=r2.x; M[1][5]=r2.y; M[2][5]=r2.z; M[3][5]=r2.w;
  #pragma unroll
  for (int k = 0; k < 4; ++k) {
    #pragma unroll
    for (int i = k+1; i < 4; ++i) {
      const bool sw = fabsf(M[i][k]) > fabsf(M[k][k]);
      #pragma unroll
      for (int j = 0; j < 6; ++j) {
        const float a_ = M[k][j], b_ = M[i][j];
        M[k][j] = sw ? b_ : a_;
        M[i][j] = sw ? a_ : b_;
      }
    }
    const float inv = __builtin_amdgcn_rcpf(M[k][k]);
    #pragma unroll
    for (int i = k+1; i < 4; ++i) {
      const float f = M[i][k] * inv;
      #pragma unroll
      for (int j = k+1; j < 6; ++j) M[i][j] = fmaf(-f, M[k][j], M[i][j]);
    }
  }
  const float i33 = __builtin_amdgcn_rcpf(M[3][3]);
  const float i22 = __builtin_amdgcn_rcpf(M[2][2]);
  const float i11 = __builtin_amdgcn_rcpf(M[1][1]);
  const float i00 = __builtin_amdgcn_rcpf(M[0][0]);
  const float a3 = M[3][4]*i33;
  const float b3 = M[3][5]*i33;
  const float a2 = fmaf(-M[2][3],a3,M[2][4])*i22;
  const float b2 = fmaf(-M[2][3],b3,M[2][5])*i22;
  const float a1 = fmaf(-M[1][3],a3,fmaf(-M[1][2],a2,M[1][4]))*i11;
  const float b1 = fmaf(-M[1][3],b3,fmaf(-M[1][2],b2,M[1][5]))*i11;
  const float a0 = fmaf(-M[0][3],a3,fmaf(-M[0][2],a2,fmaf(-M[0][1],a1,M[0][4])))*i00;
  const float b0 = fmaf(-M[0][3],b3,fmaf(-M[0][2],b2,fmaf(-M[0][1],b1,M[0][5])))*i00;
  s1 = make_float4(-a0,-a1,-a2,-a3);
  s2 = make_float4(-b0,-b1,-b2,-b3);
}

// Load F row i (16 floats) from global A/B with wave-uniform addresses (s_load).
template <bool F32>
__device__ __forceinline__ void load_frow(const float* Af, const float* Bf,
                                          const unsigned short* Ah, const unsigned short* Bh,
                                          int i, float* fr) {
  if (F32) {
    const float4 r0 = *(const float4*)(Af + i*12);
    const float4 r1 = *(const float4*)(Af + i*12 + 4);
    const float4 r2 = *(const float4*)(Af + i*12 + 8);
    const float4 rb = *(const float4*)(Bf + i*4);
    fr[0]=r0.x; fr[1]=r0.y; fr[2]=r0.z; fr[3]=r0.w;
    fr[4]=r1.x; fr[5]=r1.y; fr[6]=r1.z; fr[7]=r1.w;
    fr[8]=r2.x; fr[9]=r2.y; fr[10]=r2.z; fr[11]=r2.w;
    fr[12]=rb.x; fr[13]=rb.y; fr[14]=rb.z; fr[15]=rb.w;
  } else {
    const ushort4 h0 = *(const ushort4*)(Ah + i*12);
    const ushort4 h1 = *(const ushort4*)(Ah + i*12 + 4);
    const ushort4 h2 = *(const ushort4*)(Ah + i*12 + 8);
    const ushort4 hb = *(const ushort4*)(Bh + i*4);
    fr[0]=bf2f(h0.x); fr[1]=bf2f(h0.y); fr[2]=bf2f(h0.z); fr[3]=bf2f(h0.w);
    fr[4]=bf2f(h1.x); fr[5]=bf2f(h1.y); fr[6]=bf2f(h1.z); fr[7]=bf2f(h1.w);
    fr[8]=bf2f(h2.x); fr[9]=bf2f(h2.y); fr[10]=bf2f(h2.z); fr[11]=bf2f(h2.w);
    fr[12]=bf2f(hb.x); fr[13]=bf2f(hb.y); fr[14]=bf2f(hb.z); fr[15]=bf2f(hb.w);
  }
}

template <int MODE, bool F32>
__device__ __forceinline__ void backward_pass(
    const int c, const int b,
    const float* __restrict__ Af, const float* __restrict__ Bf,
    const unsigned short* __restrict__ Ah, const unsigned short* __restrict__ Bh,
    const float Qd, const float pc, const float* __restrict__ Fc,
    float* __restrict__ sUb, float* __restrict__ qtb, float* __restrict__ qub,
    float* __restrict__ gbl,
    float* __restrict__ wsf, unsigned short* __restrict__ wsh)
{
  float Vn[12];
  #pragma unroll
  for (int i = 0; i < 12; ++i) Vn[i] = 0.f;
  float vn = 0.f;

  for (int it = 0; it < TT; ++it) {
    // opaque SGPR zero: per-step uniform F loads, LICM blocked
    int zof = 0;
    __asm__ volatile("" : "+s"(zof));
    const float* Afo = Af + zof;
    const float* Bfo = Bf + zof;
    const unsigned short* Aho = Ah + zof;
    const unsigned short* Bho = Bh + zof;

    // ---- phase 1: U row c = Vn^T F (packed f32x2) + vn publish (same barrier)
    f32x2 U2[8];
    #pragma unroll
    for (int k = 0; k < 8; ++k) U2[k] = (f32x2){0.f, 0.f};
    #pragma unroll
    for (int j = 0; j < 12; ++j) {
      float fr[16];
      load_frow<F32>(Afo, Bfo, Aho, Bho, j, fr);
      const f32x2 vj2 = {Vn[j], Vn[j]};
      #pragma unroll
      for (int k = 0; k < 8; ++k) {
        const f32x2 f2 = {fr[2*k], fr[2*k+1]};
        U2[k] = __builtin_elementwise_fma(f2, vj2, U2[k]);
      }
    }
    if (c < 12) {
      *(float4*)(sUb + c*US     ) = make_float4(U2[0].x,U2[0].y,U2[1].x,U2[1].y);
      *(float4*)(sUb + c*US +  4) = make_float4(U2[2].x,U2[2].y,U2[3].x,U2[3].y);
      *(float4*)(sUb + c*US +  8) = make_float4(U2[4].x,U2[4].y,U2[5].x,U2[5].y);
      *(float4*)(sUb + c*US + 12) = make_float4(U2[6].x,U2[6].y,U2[7].x,U2[7].y);
      sUb[240 + c] = vn;   // v rides the same barrier (slot 240..251)
    }
    __builtin_amdgcn_wave_barrier();

    // ---- phase 2: read U column c + v; qts, qtc; publish qt cols 12..15
    float Uc[12];
    #pragma unroll
    for (int i = 0; i < 12; ++i) Uc[i] = sUb[i*US + c];

    float qts = pc;
    {
      const float4 v0 = *(const float4*)(sUb + 240);
      const float4 v1 = *(const float4*)(sUb + 244);
      const float4 v2 = *(const float4*)(sUb + 248);
      qts = fmaf(Fc[0],v0.x,qts); qts = fmaf(Fc[1],v0.y,qts); qts = fmaf(Fc[2],v0.z,qts); qts = fmaf(Fc[3],v0.w,qts);
      qts = fmaf(Fc[4],v1.x,qts); qts = fmaf(Fc[5],v1.y,qts); qts = fmaf(Fc[6],v1.z,qts); qts = fmaf(Fc[7],v1.w,qts);
      qts = fmaf(Fc[8],v2.x,qts); qts = fmaf(Fc[9],v2.y,qts); qts = fmaf(Fc[10],v2.z,qts); qts = fmaf(Fc[11],v2.w,qts);
    }

    f32x2 qt2[8];
    #pragma unroll
    for (int k = 0; k < 8; ++k) qt2[k] = (f32x2){0.f, 0.f};
    #pragma unroll
    for (int i = 0; i < 12; ++i) {
      float fr[16];
      load_frow<F32>(Afo, Bfo, Aho, Bho, i, fr);
      const f32x2 ui2 = {Uc[i], Uc[i]};
      #pragma unroll
      for (int k = 0; k < 8; ++k) {
        const f32x2 f2 = {fr[2*k], fr[2*k+1]};
        qt2[k] = __builtin_elementwise_fma(f2, ui2, qt2[k]);
      }
    }
    float qtc[16];
    #pragma unroll
    for (int a = 0; a < 16; ++a) {
      qtc[a] = (a & 1) ? qt2[a>>1].y : qt2[a>>1].x;
      qtc[a] += (a == c) ? Qd : 0.f;
    }

    if (c >= 12) {
      float* qa = qtb + (c-12)*QS;
      *(float4*)(qa     ) = make_float4(qtc[0],qtc[1],qtc[2],qtc[3]);
      *(float4*)(qa +  4) = make_float4(qtc[4],qtc[5],qtc[6],qtc[7]);
      *(float4*)(qa +  8) = make_float4(qtc[8],qtc[9],qtc[10],qtc[11]);
      *(float4*)(qa + 12) = make_float4(qtc[12],qtc[13],qtc[14],qtc[15]);
      qub[c-12] = qts;
    }
    __builtin_amdgcn_wave_barrier();

    // ---- phase 3: LU solve, gains, Vn/vn update
    const float4 q0 = *(const float4*)(qtb + 0*QS + 12);
    const float4 q1 = *(const float4*)(qtb + 1*QS + 12);
    const float4 q2 = *(const float4*)(qtb + 2*QS + 12);
    const float4 q3 = *(const float4*)(qtb + 3*QS + 12);
    const float4 quv = *(const float4*)(qub);

    float4 Kc, kf;
    lu46(q0,q1,q2,q3, make_float4(qtc[12],qtc[13],qtc[14],qtc[15]), quv, Kc, kf);

    // store gains: [t][b][col 0..12][4], col 12 = kff; t = TT-1-it
    if (c < 13) {
      float4 gw;
      gw.x = (c < 12) ? Kc.x : kf.x;
      gw.y = (c < 12) ? Kc.y : kf.y;
      gw.z = (c < 12) ? Kc.z : kf.z;
      gw.w = (c < 12) ? Kc.w : kf.w;
      if (MODE == 2) {
        *(float4*)(gbl + (TT-1-it)*52 + c*4) = gw;
      } else {
        const size_t off = ((size_t)(TT-1-it)*NBB + b)*52 + (size_t)c*4;
        if (MODE == 1) {
          ushort4 us;
          us.x = f2bf(gw.x); us.y = f2bf(gw.y); us.z = f2bf(gw.z); us.w = f2bf(gw.w);
          *(ushort4*)(wsh + off) = us;
        } else {
          *(float4*)(wsf + off) = gw;
        }
      }
    }

    // Vn[:,c] = Qxx[:,c] + Qxu*K[:,c] — packed
    f32x2 Vn2[6];
    #pragma unroll
    for (int k = 0; k < 6; ++k) Vn2[k] = (f32x2){qtc[2*k], qtc[2*k+1]};
    #pragma unroll
    for (int u = 0; u < 4; ++u) {
      const float ku = (u==0)?Kc.x:((u==1)?Kc.y:((u==2)?Kc.z:Kc.w));
      const f32x2 ku2 = {ku, ku};
      const float4 a0 = *(const float4*)(qtb + u*QS);
      const float4 a1 = *(const float4*)(qtb + u*QS + 4);
      const float4 a2 = *(const float4*)(qtb + u*QS + 8);
      Vn2[0] = __builtin_elementwise_fma((f32x2){a0.x,a0.y}, ku2, Vn2[0]);
      Vn2[1] = __builtin_elementwise_fma((f32x2){a0.z,a0.w}, ku2, Vn2[1]);
      Vn2[2] = __builtin_elementwise_fma((f32x2){a1.x,a1.y}, ku2, Vn2[2]);
      Vn2[3] = __builtin_elementwise_fma((f32x2){a1.z,a1.w}, ku2, Vn2[3]);
      Vn2[4] = __builtin_elementwise_fma((f32x2){a2.x,a2.y}, ku2, Vn2[4]);
      Vn2[5] = __builtin_elementwise_fma((f32x2){a2.z,a2.w}, ku2, Vn2[5]);
    }
    #pragma unroll
    for (int i = 0; i < 12; ++i) Vn[i] = (i & 1) ? Vn2[i>>1].y : Vn2[i>>1].x;

    // vn = qts + Qxu[c,:].kff  (Qxu[c,u] = qtc[12+u] by symmetry)
    vn = qts;
    vn = fmaf(qtc[12],kf.x,vn); vn = fmaf(qtc[13],kf.y,vn);
    vn = fmaf(qtc[14],kf.z,vn); vn = fmaf(qtc[15],kf.w,vn);
    __builtin_amdgcn_wave_barrier();
  }
}

// MODE: 0 = f32 gains in d_ws, 1 = bf16 gains in d_ws, 2 = gains in LDS
template <int MODE>
__global__ __launch_bounds__(64, 2) void mpc_kernel(
    const void* __restrict__ x_init, const void* __restrict__ Qm,
    const void* __restrict__ pm, const void* __restrict__ Am,
    const void* __restrict__ Bm, void* __restrict__ outv,
    void* __restrict__ wsv)
{
  __shared__ float sF[192];     // col-major (Fc init only)
  __shared__ float sFr[320];    // row-major stride 20 (forward pass)
  __shared__ float sU[4*UES];   // per-elem U rows (stride US) + v at 240
  __shared__ float sQt[4*QTE];  // per-elem Qt cols 12..15
  __shared__ float squ[4*20];
  __shared__ float sx[4*20];
  __shared__ float sG[(MODE == 2) ? (4*2600) : 4];

  const int tid = threadIdx.x;
  const int c = tid & 15;
  const int g = tid >> 4;
  const int b = (int)blockIdx.x * 4 + g;

  // ---- runtime dtype detection (wave-uniform) ----
  bool isf32;
  {
    const unsigned int* aw = (const unsigned int*)Am;
    int insane = 0;
    #pragma unroll 4
    for (int k = 0; k < 72; ++k) {
      const unsigned int w = aw[k];
      const unsigned short h0 = (unsigned short)(w & 0xFFFFu);
      const unsigned short h1 = (unsigned short)(w >> 16);
      const int e0 = (h0 >> 7) & 0xFF, e1 = (h1 >> 7) & 0xFF;
      insane += (((h0 & 0x7FFF) != 0) && (e0 < 107 || e0 > 132)) ? 1 : 0;
      insane += (((h1 & 0x7FFF) != 0) && (e1 < 107 || e1 > 132)) ? 1 : 0;
    }
    isf32 = (insane > 8);
  }

  const float* const xf = (const float*)x_init;
  const float* const Qf = (const float*)Qm;
  const float* const pf = (const float*)pm;
  const float* const Af = (const float*)Am;
  const float* const Bf = (const float*)Bm;
  const unsigned short* const xh = (const unsigned short*)x_init;
  const unsigned short* const Qh = (const unsigned short*)Qm;
  const unsigned short* const ph = (const unsigned short*)pm;
  const unsigned short* const Ah = (const unsigned short*)Am;
  const unsigned short* const Bh = (const unsigned short*)Bm;

  // ---- stage F (Fc + forward rows) ----
  for (int idx = tid; idx < 320; idx += 64) {
    const int i_ = idx / 20, a_ = idx - i_ * 20;
    float fv = 0.f;
    if (i_ < 12 && a_ < 16) {
      if (a_ < 12) fv = isf32 ? Af[i_*12 + a_] : bf2f(Ah[i_*12 + a_]);
      else         fv = isf32 ? Bf[i_*4 + (a_-12)] : bf2f(Bh[i_*4 + (a_-12)]);
    }
    sFr[idx] = fv;
  }
  for (int idx = tid; idx < 192; idx += 64) {
    const int a_ = idx / 12, i_ = idx - a_ * 12;
    float fv;
    if (a_ < 12) fv = isf32 ? Af[i_*12 + a_] : bf2f(Ah[i_*12 + a_]);
    else         fv = isf32 ? Bf[i_*4 + (a_-12)] : bf2f(Bh[i_*4 + (a_-12)]);
    sF[idx] = fv;
  }
  __syncthreads();

  float Fc[12];
  #pragma unroll
  for (int i = 0; i < 12; ++i) Fc[i] = sF[c*12 + i];
  const float Qd = isf32 ? Qf[b*16 + c] : bf2f(Qh[b*16 + c]);
  const float pc = isf32 ? pf[b*16 + c] : bf2f(ph[b*16 + c]);

  float* const sUb = &sU[g*UES];
  float* const qtb = &sQt[g*QTE];
  float* const qub = &squ[g*20];
  float* const sxg = &sx[g*20];
  float* const gbl = (MODE == 2) ? &sG[g*2600] : nullptr;

  float* const wsf = (float*)wsv;
  unsigned short* const wsh = (unsigned short*)wsv;

  if (isf32) {
    backward_pass<MODE, true >(c, b, Af, Bf, Ah, Bh, Qd, pc, Fc, sUb, qtb, qub, gbl, wsf, wsh);
  } else {
    backward_pass<MODE, false>(c, b, Af, Bf, Ah, Bh, Qd, pc, Fc, sUb, qtb, qub, gbl, wsf, wsh);
  }

  // ----------------- forward rollout: depth-2 gain prefetch ring -----------------
  if (MODE != 2) __threadfence();  // drain own gain stores before reading back

  float xc = 0.f;
  if (c < 12) xc = isf32 ? xf[b*12 + c] : bf2f(xh[b*12 + c]);

  float* const outf = (float*)outv;
  unsigned short* const outh = (unsigned short*)outv;

  auto loadg = [&](int t) -> float4 {
    if (c >= 13) return make_float4(0.f,0.f,0.f,0.f);
    if (MODE == 2) return *(const float4*)(gbl + t*52 + c*4);
    const size_t off = ((size_t)t*NBB + b)*52 + (size_t)c*4;
    if (MODE == 1) {
      const ushort4 us = *(const ushort4*)(wsh + off);
      return make_float4(bf2f(us.x),bf2f(us.y),bf2f(us.z),bf2f(us.w));
    }
    return *(const float4*)(wsf + off);
  };

  auto body = [&](int t, const float4 gv) {
    if (c < 12) sxg[c] = xc;
    __builtin_amdgcn_wave_barrier();
    const float4 x0 = *(const float4*)(sxg);
    const float4 x1 = *(const float4*)(sxg + 4);
    const float4 x2 = *(const float4*)(sxg + 8);

    const float s = (c < 12) ? xc : 1.0f;
    const float u0 = rrsum16(gv.x*s), u1 = rrsum16(gv.y*s), u2 = rrsum16(gv.z*s), u3 = rrsum16(gv.w*s);

    if (c == 0) {
      const size_t o4 = ((size_t)t*NBB + b)*4;
      if (isf32) {
        *(float4*)(outf + o4) = make_float4(u0,u1,u2,u3);
      } else {
        ushort4 us;
        us.x = f2bf(u0); us.y = f2bf(u1); us.z = f2bf(u2); us.w = f2bf(u3);
        *(ushort4*)(outh + o4) = us;
      }
    }
    const float4 fr0 = *(const float4*)(sFr + c*20);
    const float4 fr1 = *(const float4*)(sFr + c*20 + 4);
    const float4 fr2 = *(const float4*)(sFr + c*20 + 8);
    const float4 frB = *(const float4*)(sFr + c*20 + 12);
    float xp = fr0.x*x0.x;
    xp = fmaf(fr0.y,x0.y,xp); xp = fmaf(fr0.z,x0.z,xp); xp = fmaf(fr0.w,x0.w,xp);
    xp = fmaf(fr1.x,x1.x,xp); xp = fmaf(fr1.y,x1.y,xp); xp = fmaf(fr1.z,x1.z,xp); xp = fmaf(fr1.w,x1.w,xp);
    xp = fmaf(fr2.x,x2.x,xp); xp = fmaf(fr2.y,x2.y,xp); xp = fmaf(fr2.z,x2.z,xp); xp = fmaf(fr2.w,x2.w,xp);
    xp = fmaf(frB.x,u0,xp); xp = fmaf(frB.y,u1,xp); xp = fmaf(frB.z,u2,xp); xp = fmaf(frB.w,u3,xp);
    __builtin_amdgcn_wave_barrier();   // next step's sxg write must follow this step's reads
    xc = xp;
  };

  // depth-2 prefetch ring, unroll-2 (TT = 50, even)
  float4 g0 = loadg(0);
  float4 g1 = loadg(1);
  for (int t = 0; t < TT; t += 2) {
    body(t, g0);
    if (t + 2 < TT) g0 = loadg(t + 2);
    body(t + 1, g1);
    if (t + 3 < TT) g1 = loadg(t + 3);
  }
}

extern "C" void kernel_launch(void* const* d_in, const int* in_sizes, int n_in,
                              void* d_out, int out_size, void* d_ws, size_t ws_size,
                              hipStream_t stream) {
  (void)in_sizes; (void)n_in; (void)out_size;
  const size_t needF = (size_t)TT * NBB * 52 * sizeof(float);          // 85.2 MB
  const size_t needH = (size_t)TT * NBB * 52 * sizeof(unsigned short); // 42.6 MB
  dim3 grid(NBB / 4), block(64);
  if (d_ws != nullptr && ws_size >= needF) {
    mpc_kernel<0><<<grid, block, 0, stream>>>(d_in[0], d_in[1], d_in[2], d_in[3], d_in[4], d_out, d_ws);
  } else if (d_ws != nullptr && ws_size >= needH) {
    mpc_kernel<1><<<grid, block, 0, stream>>>(d_in[0], d_in[1], d_in[2], d_in[3], d_in[4], d_out, d_ws);
  } else {
    mpc_kernel<2><<<grid, block, 0, stream>>>(d_in[0], d_in[1], d_in[2], d_in[3], d_in[4], d_out, d_ws);
  }
}